// Round 8
// baseline (158.881 us; speedup 1.0000x reference)
//
#include <hip/hip_runtime.h>

#define NN 100
#define EE 262144
#define NP 16

// ws float offsets:
//   P  @ 0      : NP*10000 = 160000   (scatter partial histograms)
//   D  @ 160000 : NP*100   = 1600     (scatter partial row degrees)
//   MS @ 161600 : 512                 (BN sum/sumsq; zeroed by scatter blk 0)
//   h2 @ 162112 : 12800
//   h3 @ 174912 : 25600
#define WS_D   160000
#define WS_MS  161600
#define WS_H2  162112
#define WS_H3  174912

// ---- 1. scatter: LDS hist + row-degree partials; no global atomics ----
__global__ __launch_bounds__(1024) void scatter_kernel(
    const int* __restrict__ ei, const float* __restrict__ ew,
    float* __restrict__ P, float* __restrict__ D, float* __restrict__ MS)
{
    __shared__ float hist[NN * NN];          // 40 KB
    __shared__ float part[NN][4];
    const int tid = threadIdx.x, blk = blockIdx.x;
    for (int i = tid; i < 2500; i += 1024)
        ((float4*)hist)[i] = make_float4(0.f, 0.f, 0.f, 0.f);
    if (blk == 0 && tid < 128)
        ((float4*)MS)[tid] = make_float4(0.f, 0.f, 0.f, 0.f);
    __syncthreads();
    const int base = blk * 4096;             // 4096 quads = 16384 edges / block
#pragma unroll
    for (int it = 0; it < 4; ++it) {
        int q = base + it * 1024 + tid;
        int4   s4 = ((const int4*)ei)[q];
        int4   d4 = ((const int4*)(ei + EE))[q];
        float4 w4 = ((const float4*)ew)[q];
        atomicAdd(&hist[d4.x * NN + s4.x], w4.x);    // ds_add_f32
        atomicAdd(&hist[d4.y * NN + s4.y], w4.y);
        atomicAdd(&hist[d4.z * NN + s4.z], w4.z);
        atomicAdd(&hist[d4.w * NN + s4.w], w4.w);
    }
    __syncthreads();
    for (int i = tid; i < 2500; i += 1024)
        ((float4*)(P + blk * 10000))[i] = ((const float4*)hist)[i];
    if (tid < 400) {                         // row-degree partials
        int row = tid >> 2, q = tid & 3;
        const float* r = hist + row * NN + q * 25;
        float s = 0.f;
#pragma unroll
        for (int k = 0; k < 25; ++k) s += r[k];
        part[row][q] = s;
    }
    __syncthreads();
    if (tid < NN)
        D[blk * NN + tid] = part[tid][0] + part[tid][1] + part[tid][2] + part[tid][3];
}

// ---- 2. mid1: full A + full L1 (redundant) + own h2 row (100 blocks) ----
__global__ __launch_bounds__(256) void mid1_kernel(
    const float* __restrict__ P, const float* __restrict__ D,
    const float* __restrict__ x,
    const float* __restrict__ W1, const float* __restrict__ b1,
    const float* __restrict__ W2, const float* __restrict__ b2,
    float* __restrict__ h2g)
{
    __shared__ float A[NN * NN];             // 40 KB
    __shared__ float xl[NN * 28];
    __shared__ float g1[NN * 28];
    __shared__ float W1l[27 * 64];
    __shared__ float b1l[64];
    __shared__ float h1l[NN * 64];           // 25.6 KB
    __shared__ float dv[NN];
    __shared__ float g2[64];
    const int tid = threadIdx.x, d = blockIdx.x;

    for (int i = tid; i < NN * 28; i += 256) {
        int n = i / 28, c = i - n * 28;
        xl[i] = (c < 27) ? x[n * 27 + c] : 0.f;
    }
    for (int i = tid; i < 27 * 64; i += 256) W1l[i] = W1[i];
    if (tid < 64) b1l[tid] = b1[tid];
    if (tid < NN) {
        float deg = 1.f;
#pragma unroll
        for (int p = 0; p < NP; ++p) deg += D[p * NN + tid];
        dv[tid] = rsqrtf(deg);
    }
    __syncthreads();

    // A = dinv ⊗ dinv · ΣP (+ dinv² diag)
    for (int i4 = tid; i4 < 2500; i4 += 256) {
        float4 s = ((const float4*)P)[i4];
#pragma unroll
        for (int p = 1; p < NP; ++p) {
            float4 b = ((const float4*)P)[p * 2500 + i4];
            s.x += b.x; s.y += b.y; s.z += b.z; s.w += b.w;
        }
        int r = i4 / 25, c0 = (i4 - r * 25) * 4;
        float dr = dv[r], dd = dr * dr;
        float4 a;
        a.x = dr * dv[c0 + 0] * s.x; if (r == c0 + 0) a.x += dd;
        a.y = dr * dv[c0 + 1] * s.y; if (r == c0 + 1) a.y += dd;
        a.z = dr * dv[c0 + 2] * s.z; if (r == c0 + 2) a.z += dd;
        a.w = dr * dv[c0 + 3] * s.w; if (r == c0 + 3) a.w += dd;
        ((float4*)A)[i4] = a;
    }
    __syncthreads();

    // g1 = A @ x (full, 4x4 register tiles; 175 jobs < 256 threads)
    if (tid < 175) {
        int nt = tid / 7, n0 = nt * 4, c0 = (tid - nt * 7) * 4;
        float acc[4][4];
#pragma unroll
        for (int r = 0; r < 4; ++r)
#pragma unroll
            for (int q = 0; q < 4; ++q) acc[r][q] = 0.f;
        for (int m = 0; m < NN; m += 4) {
            float4 a0 = *(const float4*)(A + (n0 + 0) * NN + m);
            float4 a1 = *(const float4*)(A + (n0 + 1) * NN + m);
            float4 a2 = *(const float4*)(A + (n0 + 2) * NN + m);
            float4 a3 = *(const float4*)(A + (n0 + 3) * NN + m);
            float4 x0 = *(const float4*)(xl + (m + 0) * 28 + c0);
            float4 x1 = *(const float4*)(xl + (m + 1) * 28 + c0);
            float4 x2 = *(const float4*)(xl + (m + 2) * 28 + c0);
            float4 x3 = *(const float4*)(xl + (m + 3) * 28 + c0);
#define GROW(r, ar) \
            acc[r][0] += ar.x*x0.x + ar.y*x1.x + ar.z*x2.x + ar.w*x3.x; \
            acc[r][1] += ar.x*x0.y + ar.y*x1.y + ar.z*x2.y + ar.w*x3.y; \
            acc[r][2] += ar.x*x0.z + ar.y*x1.z + ar.z*x2.z + ar.w*x3.z; \
            acc[r][3] += ar.x*x0.w + ar.y*x1.w + ar.z*x2.w + ar.w*x3.w;
            GROW(0, a0) GROW(1, a1) GROW(2, a2) GROW(3, a3)
#undef GROW
        }
#pragma unroll
        for (int r = 0; r < 4; ++r)
            *(float4*)(g1 + (n0 + r) * 28 + c0) =
                make_float4(acc[r][0], acc[r][1], acc[r][2], acc[r][3]);
    }
    __syncthreads();

    // h1 = relu(g1 @ W1 + b1) (full) -> LDS
    // FIX: 400 tile-jobs on 256 threads -> grid-stride loop (was if(tid<400))
    for (int t = tid; t < 400; t += 256) {
        int nt = t / 16, n0 = nt * 4, j0 = (t - nt * 16) * 4;
        float acc[4][4];
#pragma unroll
        for (int r = 0; r < 4; ++r)
#pragma unroll
            for (int q = 0; q < 4; ++q) acc[r][q] = 0.f;
        for (int c = 0; c < 24; c += 4) {
            float4 w0 = *(const float4*)(W1l + (c + 0) * 64 + j0);
            float4 w1 = *(const float4*)(W1l + (c + 1) * 64 + j0);
            float4 w2 = *(const float4*)(W1l + (c + 2) * 64 + j0);
            float4 w3 = *(const float4*)(W1l + (c + 3) * 64 + j0);
            float4 g0 = *(const float4*)(g1 + (n0 + 0) * 28 + c);
            float4 g1_ = *(const float4*)(g1 + (n0 + 1) * 28 + c);
            float4 g2_ = *(const float4*)(g1 + (n0 + 2) * 28 + c);
            float4 g3_ = *(const float4*)(g1 + (n0 + 3) * 28 + c);
#define TROW(r, gr) \
            acc[r][0] += gr.x*w0.x + gr.y*w1.x + gr.z*w2.x + gr.w*w3.x; \
            acc[r][1] += gr.x*w0.y + gr.y*w1.y + gr.z*w2.y + gr.w*w3.y; \
            acc[r][2] += gr.x*w0.z + gr.y*w1.z + gr.z*w2.z + gr.w*w3.z; \
            acc[r][3] += gr.x*w0.w + gr.y*w1.w + gr.z*w2.w + gr.w*w3.w;
            TROW(0, g0) TROW(1, g1_) TROW(2, g2_) TROW(3, g3_)
#undef TROW
        }
#pragma unroll
        for (int c = 24; c < 27; ++c) {
            float4 wq = *(const float4*)(W1l + c * 64 + j0);
#pragma unroll
            for (int r = 0; r < 4; ++r) {
                float gv = g1[(n0 + r) * 28 + c];
                acc[r][0] += gv * wq.x; acc[r][1] += gv * wq.y;
                acc[r][2] += gv * wq.z; acc[r][3] += gv * wq.w;
            }
        }
        float4 bq = *(const float4*)(b1l + j0);
#pragma unroll
        for (int r = 0; r < 4; ++r) {
            float4 v;
            v.x = fmaxf(acc[r][0] + bq.x, 0.f); v.y = fmaxf(acc[r][1] + bq.y, 0.f);
            v.z = fmaxf(acc[r][2] + bq.z, 0.f); v.w = fmaxf(acc[r][3] + bq.w, 0.f);
            *(float4*)(h1l + (n0 + r) * 64 + j0) = v;
        }
    }
    __syncthreads();

    // g2 = A[d] @ h1 (own row only)
    if (tid < 64) {
        const float* Ar = A + d * NN;
        float acc = 0.f;
#pragma unroll 4
        for (int m = 0; m < NN; ++m) acc += Ar[m] * h1l[m * 64 + tid];
        g2[tid] = acc;
    }
    __syncthreads();

    // h2 row = relu(g2 @ W2 + b2)
    if (tid < 128) {
        float acc = b2[tid];
#pragma unroll 8
        for (int c = 0; c < 64; ++c) acc += g2[c] * W2[c * 128 + tid];
        h2g[d * 128 + tid] = fmaxf(acc, 0.f);
    }
}

// ---- 3. l3: recompute A-row, g3, h3 + BN stats (100 blocks) ----
__global__ __launch_bounds__(256) void l3_kernel(
    const float* __restrict__ P, const float* __restrict__ D,
    const float* __restrict__ h2g,
    const float* __restrict__ W3, const float* __restrict__ b3,
    float* __restrict__ h3g, float* __restrict__ MS)
{
    __shared__ float h2l[NN * 128];          // 51.2 KB
    __shared__ float dv[NN];
    __shared__ float Ar[NN];
    __shared__ float g3[128];
    const int tid = threadIdx.x, d = blockIdx.x;

    for (int i = tid; i < NN * 32; i += 256)
        ((float4*)h2l)[i] = ((const float4*)h2g)[i];
    if (tid < NN) {
        float deg = 1.f;
#pragma unroll
        for (int p = 0; p < NP; ++p) deg += D[p * NN + tid];
        dv[tid] = rsqrtf(deg);
    }
    __syncthreads();
    if (tid < NN) {
        float s = 0.f;
#pragma unroll
        for (int p = 0; p < NP; ++p) s += P[p * 10000 + d * NN + tid];
        float v = dv[d] * dv[tid] * s;
        if (tid == d) v += dv[d] * dv[d];
        Ar[tid] = v;
    }
    __syncthreads();
    if (tid < 128) {
        float acc = 0.f;
#pragma unroll 4
        for (int m = 0; m < NN; ++m) acc += Ar[m] * h2l[m * 128 + tid];
        g3[tid] = acc;
    }
    __syncthreads();
    {
        int j = tid;
        float acc = b3[j];
#pragma unroll 8
        for (int c = 0; c < 128; ++c) acc += g3[c] * W3[c * 256 + j];
        float v = fmaxf(acc, 0.f);
        h3g[d * 256 + j] = v;
        atomicAdd(&MS[j], v);
        atomicAdd(&MS[256 + j], v * v);
    }
}

// ---- 4. tail: BN fold + redundant y + own out dot (128 blocks) ----
__global__ __launch_bounds__(256) void tail_kernel(
    const float* __restrict__ h3g, const float* __restrict__ MS,
    const float* __restrict__ gamma, const float* __restrict__ beta,
    const float* __restrict__ lw1, const float* __restrict__ lb1,
    const float* __restrict__ lw2, const float* __restrict__ lb2,
    float* __restrict__ out)
{
    __shared__ float sc[256], sh[256];
    __shared__ float wsc[2560];              // sc-folded lw1
    __shared__ float cst[10];                // sh·lw1 + lb1
    __shared__ float yl[1000];
    __shared__ float partw[4];
    const int tid = threadIdx.x, j = blockIdx.x;

    {
        float s1 = MS[tid], s2 = MS[256 + tid];
        float mu  = s1 * 0.01f;
        float var = s2 * 0.01f - mu * mu;
        float s   = gamma[tid] * rsqrtf(var + 1e-5f);
        sc[tid] = s;
        sh[tid] = beta[tid] - mu * s;
    }
    __syncthreads();
    for (int i = tid; i < 2560; i += 256) wsc[i] = sc[i & 255] * lw1[i];
    if (tid < 10) {
        float a = lb1[tid];
        const float* w = lw1 + tid * 256;
#pragma unroll 4
        for (int c = 0; c < 256; ++c) a += sh[c] * w[c];
        cst[tid] = a;
    }
    __syncthreads();

    // y[1000] redundant: 250 jobs of 2n x 2k register tiles
    if (tid < 250) {
        int n0 = (tid / 5) * 2, k0 = (tid % 5) * 2;
        float a00 = 0.f, a01 = 0.f, a10 = 0.f, a11 = 0.f;
        for (int c = 0; c < 256; c += 4) {
            float4 hA = *(const float4*)(h3g + n0 * 256 + c);
            float4 hB = *(const float4*)(h3g + (n0 + 1) * 256 + c);
            float4 wA = *(const float4*)(wsc + k0 * 256 + c);
            float4 wB = *(const float4*)(wsc + (k0 + 1) * 256 + c);
            a00 += hA.x*wA.x + hA.y*wA.y + hA.z*wA.z + hA.w*wA.w;
            a01 += hA.x*wB.x + hA.y*wB.y + hA.z*wB.z + hA.w*wB.w;
            a10 += hB.x*wA.x + hB.y*wA.y + hB.z*wA.z + hB.w*wA.w;
            a11 += hB.x*wB.x + hB.y*wB.y + hB.z*wB.z + hB.w*wB.w;
        }
        yl[n0 * 10 + k0]           = fmaxf(a00 + cst[k0], 0.f);
        yl[n0 * 10 + k0 + 1]       = fmaxf(a01 + cst[k0 + 1], 0.f);
        yl[(n0 + 1) * 10 + k0]     = fmaxf(a10 + cst[k0], 0.f);
        yl[(n0 + 1) * 10 + k0 + 1] = fmaxf(a11 + cst[k0 + 1], 0.f);
    }
    __syncthreads();

    float acc = 0.f;
    if (tid < 250) {
        float4 a = ((const float4*)yl)[tid];
        float4 b = ((const float4*)(lw2 + j * 1000))[tid];
        acc = a.x * b.x + a.y * b.y + a.z * b.z + a.w * b.w;
    }
#pragma unroll
    for (int off = 32; off; off >>= 1) acc += __shfl_down(acc, off);
    if ((tid & 63) == 0) partw[tid >> 6] = acc;
    __syncthreads();
    if (tid == 0)
        out[j] = partw[0] + partw[1] + partw[2] + partw[3] + lb2[j];
}

extern "C" void kernel_launch(void* const* d_in, const int* in_sizes, int n_in,
                              void* d_out, int out_size, void* d_ws, size_t ws_size,
                              hipStream_t stream) {
    const float* x     = (const float*)d_in[0];
    const int*   ei    = (const int*)d_in[1];
    const float* ew    = (const float*)d_in[2];
    const float* W1    = (const float*)d_in[3];
    const float* b1    = (const float*)d_in[4];
    const float* W2    = (const float*)d_in[5];
    const float* b2    = (const float*)d_in[6];
    const float* W3    = (const float*)d_in[7];
    const float* b3    = (const float*)d_in[8];
    const float* gamma = (const float*)d_in[9];
    const float* beta  = (const float*)d_in[10];
    const float* lw1   = (const float*)d_in[11];
    const float* lb1   = (const float*)d_in[12];
    const float* lw2   = (const float*)d_in[13];
    const float* lb2   = (const float*)d_in[14];

    float* ws  = (float*)d_ws;
    float* P   = ws;
    float* D   = ws + WS_D;
    float* MS  = ws + WS_MS;
    float* h2  = ws + WS_H2;
    float* h3  = ws + WS_H3;
    float* out = (float*)d_out;

    scatter_kernel<<<NP, 1024, 0, stream>>>(ei, ew, P, D, MS);
    mid1_kernel<<<NN, 256, 0, stream>>>(P, D, x, W1, b1, W2, b2, h2);
    l3_kernel<<<NN, 256, 0, stream>>>(P, D, h2, W3, b3, h3, MS);
    tail_kernel<<<128, 256, 0, stream>>>(h3, MS, gamma, beta, lw1, lb1,
                                         lw2, lb2, out);
}